// Round 5
// baseline (900.552 us; speedup 1.0000x reference)
//
#include <hip/hip_runtime.h>
#include <hip/hip_bf16.h>

// GAT layer, B=8 N=4096 F=128 U=64, ALL I/O float32.
// out = relu( softmax_row( lrelu(s_i + t_j) masked by A ) @ X ),  X = H@W.
// A is the only O(N^2) tensor: 512 MB f32 -> ~86 us HBM floor.
// R5: MEASUREMENT ROUND. attn launched TWICE (idempotent) so its true cost is
// R5_dur - R4_dur; also removed nt from A loads (R3 measured nt as +18 us).

#define NTOK 4096
#define FDIM 128
#define UDIM 64
#define BATCH 8

typedef __attribute__((ext_vector_type(8))) short short8;
typedef __attribute__((ext_vector_type(4))) float f32x4;

union PackU { unsigned u[4]; short8 s; };

// round-to-nearest-even f32 -> bf16 (used in prep only)
__device__ __forceinline__ unsigned short f2bf(float x) {
    unsigned u = __float_as_uint(x);
    return (unsigned short)((u + 0x7fffu + ((u >> 16) & 1u)) >> 16);
}

// ---------------- kernel 1: X = H@W (MFMA), s,t (pre-scaled by log2e) ------
__global__ __launch_bounds__(256) void prep_kernel(
    const float* __restrict__ H,    // f32 [B*N, 128]
    const float* __restrict__ W,    // f32 [128, 64]
    const float* __restrict__ a1,   // f32 [64]
    const float* __restrict__ a2,   // f32 [64]
    unsigned short* __restrict__ XT,// bf16 [B, 64, N] (scratch)
    float* __restrict__ s_out,      // f32 [B*N], = (X@a1)*log2(e)
    float* __restrict__ t_out)      // f32 [B*N], = (X@a2)*log2(e)
{
    __shared__ float Xl[4][16][UDIM + 1];

    const int tid  = threadIdx.x;
    const int wave = tid >> 6, lane = tid & 63;
    const int col  = lane & 15, quad = lane >> 4;
    const int i0   = (blockIdx.x * 4 + wave) * 16;

    f32x4 acc0 = {0,0,0,0}, acc1 = {0,0,0,0}, acc2 = {0,0,0,0}, acc3 = {0,0,0,0};
    const float* hrow = H + (size_t)(i0 + col) * FDIM + quad * 8;

    #pragma unroll
    for (int kb = 0; kb < FDIM; kb += 32) {
        f32x4 h0 = *(const f32x4*)(hrow + kb);       // A[m=lane&15][k=quad*8+j]
        f32x4 h1 = *(const f32x4*)(hrow + kb + 4);
        short8 afr, b0, b1, b2, b3;
        #pragma unroll
        for (int j = 0; j < 4; ++j) {
            afr[j]     = (short)f2bf(h0[j]);
            afr[4 + j] = (short)f2bf(h1[j]);
        }
        #pragma unroll
        for (int j = 0; j < 8; ++j) {                // W tiny, L1-hot
            int k = kb + quad * 8 + j;
            b0[j] = (short)f2bf(W[k * UDIM + col]);
            b1[j] = (short)f2bf(W[k * UDIM + 16 + col]);
            b2[j] = (short)f2bf(W[k * UDIM + 32 + col]);
            b3[j] = (short)f2bf(W[k * UDIM + 48 + col]);
        }
        acc0 = __builtin_amdgcn_mfma_f32_16x16x32_bf16(afr, b0, acc0, 0, 0, 0);
        acc1 = __builtin_amdgcn_mfma_f32_16x16x32_bf16(afr, b1, acc1, 0, 0, 0);
        acc2 = __builtin_amdgcn_mfma_f32_16x16x32_bf16(afr, b2, acc2, 0, 0, 0);
        acc3 = __builtin_amdgcn_mfma_f32_16x16x32_bf16(afr, b3, acc3, 0, 0, 0);
    }
    #pragma unroll
    for (int r = 0; r < 4; ++r) {   // C/D: col(u)=lane&15 (+16/group), row=quad*4+r
        Xl[wave][quad * 4 + r][col]      = acc0[r];
        Xl[wave][quad * 4 + r][16 + col] = acc1[r];
        Xl[wave][quad * 4 + r][32 + col] = acc2[r];
        Xl[wave][quad * 4 + r][48 + col] = acc3[r];
    }
    __syncthreads();

    const int b = i0 >> 12, n0 = i0 & (NTOK - 1);
    float ps = 0.f, pt = 0.f;
    #pragma unroll
    for (int ui = 0; ui < 16; ++ui) {
        int u = quad * 16 + ui;
        float x = Xl[wave][col][u];
        ps = fmaf(x, a1[u], ps);
        pt = fmaf(x, a2[u], pt);
    }
    ps += __shfl_xor(ps, 16, 64); ps += __shfl_xor(ps, 32, 64);
    pt += __shfl_xor(pt, 16, 64); pt += __shfl_xor(pt, 32, 64);
    const float LOG2E = 1.44269504f;
    if (quad == 0) s_out[i0 + col] = ps * LOG2E;   // exp2 domain
    if (quad == 1) t_out[i0 + col] = pt * LOG2E;

    #pragma unroll
    for (int ui = 0; ui < 16; ++ui) {
        int u = quad * 16 + ui;
        XT[(size_t)(b * UDIM + u) * NTOK + n0 + col] = f2bf(Xl[wave][col][u]);
    }
}

// ---------------- kernel 2: fused mask+softmax+PV ---------------------------
// grid 512 = 8 batches x 64 row-tiles-of-64 (b = bx&7), 4 waves/block.
// Each wave: 4 row-groups of 16 x its K-chunk of 1024, step 32.
__global__ __launch_bounds__(256) void attn_kernel(
    const float* __restrict__ A,            // f32 [B, N, N] -- 512 MB stream
    const unsigned short* __restrict__ XT,  // bf16 [B, 64, N]
    const float* __restrict__ s_in,         // log2e-scaled
    const float* __restrict__ t_in,         // log2e-scaled
    float* __restrict__ out)                // f32 [B, N, 64]
{
    __shared__ float part[4][64][UDIM + 1]; // 66.6 KB: per-wave partial numerators
    __shared__ float denl[4][64];

    const int tid  = threadIdx.x;
    const int wave = tid >> 6, lane = tid & 63;
    const int bx   = blockIdx.x;
    const int b    = bx & 7;
    const int i0   = (bx >> 3) * 64;
    const int col  = lane & 15, quad = lane >> 4;
    const int kstart = wave * (NTOK / 4);

    float s_m[4];
    #pragma unroll
    for (int g = 0; g < 4; ++g) s_m[g] = s_in[b * NTOK + i0 + g * 16 + col];

    const float* ap[4];
    #pragma unroll
    for (int g = 0; g < 4; ++g)
        ap[g] = A + ((size_t)(b * NTOK + i0 + g * 16 + col)) * NTOK + kstart + quad * 8;
    const float* tptr = t_in + b * NTOK + kstart + quad * 8;
    const unsigned short* xb  = XT + (size_t)b * UDIM * NTOK + kstart + quad * 8;
    const unsigned short* xp0 = xb + (size_t)(col)      * NTOK;
    const unsigned short* xp1 = xb + (size_t)(16 + col) * NTOK;
    const unsigned short* xp2 = xb + (size_t)(32 + col) * NTOK;
    const unsigned short* xp3 = xb + (size_t)(48 + col) * NTOK;

    f32x4 acc[4][4];
    #pragma unroll
    for (int g = 0; g < 4; ++g)
        #pragma unroll
        for (int f = 0; f < 4; ++f) acc[g][f] = (f32x4){0,0,0,0};
    float den[4] = {0.f, 0.f, 0.f, 0.f};

    #pragma unroll 2
    for (int step = 0; step < 32; ++step) {
        short8 bf0 = *(const short8*)xp0;          // shared across row-groups
        short8 bf1 = *(const short8*)xp1;
        short8 bf2 = *(const short8*)xp2;
        short8 bf3 = *(const short8*)xp3;
        f32x4 t0  = *(const f32x4*)tptr;           // k = quad*8 + 0..3
        f32x4 t1  = *(const f32x4*)(tptr + 4);     // k = quad*8 + 4..7

        #pragma unroll
        for (int g = 0; g < 4; ++g) {
            f32x4 am0 = *(const f32x4*)ap[g];      // plain loads (nt was +18us in R3)
            f32x4 am1 = *(const f32x4*)(ap[g] + 4);
            unsigned uw[8];
            #pragma unroll
            for (int j = 0; j < 4; ++j) {
                float l0 = s_m[g] + t0[j], l1 = s_m[g] + t1[j];
                float e0 = fmaxf(l0, 0.2f * l0);   // lrelu commutes with log2e>0
                float e1 = fmaxf(l1, 0.2f * l1);
                float w0 = __builtin_amdgcn_exp2f(e0) * am0[j];  // masked -> exact 0
                float w1 = __builtin_amdgcn_exp2f(e1) * am1[j];
                den[g] += w0 + w1;
                uw[j]     = __float_as_uint(w0) + 0x8000u;  // round-half-up bf16
                uw[4 + j] = __float_as_uint(w1) + 0x8000u;
            }
            PackU p;   // pack hi16 pairs: afr[k]=w(k), k=quad*8+j
            p.u[0] = __builtin_amdgcn_perm(uw[1], uw[0], 0x07060302u);
            p.u[1] = __builtin_amdgcn_perm(uw[3], uw[2], 0x07060302u);
            p.u[2] = __builtin_amdgcn_perm(uw[5], uw[4], 0x07060302u);
            p.u[3] = __builtin_amdgcn_perm(uw[7], uw[6], 0x07060302u);

            acc[g][0] = __builtin_amdgcn_mfma_f32_16x16x32_bf16(p.s, bf0, acc[g][0], 0, 0, 0);
            acc[g][1] = __builtin_amdgcn_mfma_f32_16x16x32_bf16(p.s, bf1, acc[g][1], 0, 0, 0);
            acc[g][2] = __builtin_amdgcn_mfma_f32_16x16x32_bf16(p.s, bf2, acc[g][2], 0, 0, 0);
            acc[g][3] = __builtin_amdgcn_mfma_f32_16x16x32_bf16(p.s, bf3, acc[g][3], 0, 0, 0);
            ap[g] += 32;
        }
        tptr += 32; xp0 += 32; xp1 += 32; xp2 += 32; xp3 += 32;
    }

    #pragma unroll
    for (int g = 0; g < 4; ++g) {
        den[g] += __shfl_xor(den[g], 16, 64);
        den[g] += __shfl_xor(den[g], 32, 64);
        if (quad == 0) denl[wave][g * 16 + col] = den[g];
        #pragma unroll
        for (int r = 0; r < 4; ++r) {
            part[wave][g * 16 + quad * 4 + r][col]      = acc[g][0][r];
            part[wave][g * 16 + quad * 4 + r][16 + col] = acc[g][1][r];
            part[wave][g * 16 + quad * 4 + r][32 + col] = acc[g][2][r];
            part[wave][g * 16 + quad * 4 + r][48 + col] = acc[g][3][r];
        }
    }
    __syncthreads();

    // cross-wave reduce + divide + relu + store (64 rows x 64 u, coalesced)
    #pragma unroll
    for (int rep = 0; rep < 16; ++rep) {
        int e = rep * 256 + tid;
        int r = e >> 6, u = e & 63;
        float num = part[0][r][u] + part[1][r][u] + part[2][r][u] + part[3][r][u];
        float dd  = denl[0][r] + denl[1][r] + denl[2][r] + denl[3][r];
        float o   = fmaxf(num / dd, 0.f);
        __builtin_nontemporal_store(o, &out[(size_t)(b * NTOK + i0 + r) * UDIM + u]);
    }
}

extern "C" void kernel_launch(void* const* d_in, const int* in_sizes, int n_in,
                              void* d_out, int out_size, void* d_ws, size_t ws_size,
                              hipStream_t stream) {
    const float* H  = (const float*)d_in[0];
    const float* A  = (const float*)d_in[1];
    const float* W  = (const float*)d_in[2];
    const float* a1 = (const float*)d_in[3];
    const float* a2 = (const float*)d_in[4];
    float* out = (float*)d_out;

    char* ws = (char*)d_ws;
    unsigned short* XT = (unsigned short*)ws;                               // 4 MB bf16
    float* s = (float*)(ws + (size_t)BATCH * UDIM * NTOK * 2);              // 128 KB
    float* t = (float*)(ws + (size_t)BATCH * UDIM * NTOK * 2 + (size_t)BATCH * NTOK * 4);

    prep_kernel<<<512, 256, 0, stream>>>(H, W, a1, a2, XT, s, t);
    // MEASUREMENT: attn launched twice (idempotent -> identical output).
    // attn_dur = dur_us(R5) - dur_us(R4) + ~18us(nt removal). Revert next round.
    attn_kernel<<<512, 256, 0, stream>>>(A, XT, s, t, out);
    attn_kernel<<<512, 256, 0, stream>>>(A, XT, s, t, out);
}

// Round 6
// 778.080 us; speedup vs baseline: 1.1574x; 1.1574x over previous
//
#include <hip/hip_runtime.h>
#include <hip/hip_bf16.h>

// GAT layer, B=8 N=4096 F=128 U=64, ALL I/O float32.
// out = relu( softmax_row( lrelu(s_i + t_j) masked by A ) @ X ),  X = H@W.
// A is the only O(N^2) tensor: 512 MB f32 -> ~86 us HBM floor (~81 us/CU).
// R5 measured attn = 160 us (3.2 TB/s on A, 51% of achievable): latency-bound
// at 2 waves/SIMD (66 KB LDS cap).
// R6: row-split waves -- each wave owns 16 rows x full K, so no cross-wave
// reduction: LDS = 0, den via shuffles, epilogue from registers. Occupancy
// VGPR-bound (~16-20 waves/CU). Explicit 1-step A prefetch.

#define NTOK 4096
#define FDIM 128
#define UDIM 64
#define BATCH 8

typedef __attribute__((ext_vector_type(8))) short short8;
typedef __attribute__((ext_vector_type(4))) float f32x4;

union PackU { unsigned u[4]; short8 s; };

// round-to-nearest-even f32 -> bf16 (prep only)
__device__ __forceinline__ unsigned short f2bf(float x) {
    unsigned u = __float_as_uint(x);
    return (unsigned short)((u + 0x7fffu + ((u >> 16) & 1u)) >> 16);
}

// ---------------- kernel 1: X = H@W (MFMA), s,t (pre-scaled by log2e) ------
__global__ __launch_bounds__(256) void prep_kernel(
    const float* __restrict__ H,    // f32 [B*N, 128]
    const float* __restrict__ W,    // f32 [128, 64]
    const float* __restrict__ a1,   // f32 [64]
    const float* __restrict__ a2,   // f32 [64]
    unsigned short* __restrict__ XT,// bf16 [B, 64, N] (scratch)
    float* __restrict__ s_out,      // f32 [B*N], = (X@a1)*log2(e)
    float* __restrict__ t_out)      // f32 [B*N], = (X@a2)*log2(e)
{
    __shared__ float Xl[4][16][UDIM + 1];

    const int tid  = threadIdx.x;
    const int wave = tid >> 6, lane = tid & 63;
    const int col  = lane & 15, quad = lane >> 4;
    const int i0   = (blockIdx.x * 4 + wave) * 16;

    f32x4 acc0 = {0,0,0,0}, acc1 = {0,0,0,0}, acc2 = {0,0,0,0}, acc3 = {0,0,0,0};
    const float* hrow = H + (size_t)(i0 + col) * FDIM + quad * 8;

    #pragma unroll
    for (int kb = 0; kb < FDIM; kb += 32) {
        f32x4 h0 = *(const f32x4*)(hrow + kb);       // A[m=lane&15][k=quad*8+j]
        f32x4 h1 = *(const f32x4*)(hrow + kb + 4);
        short8 afr, b0, b1, b2, b3;
        #pragma unroll
        for (int j = 0; j < 4; ++j) {
            afr[j]     = (short)f2bf(h0[j]);
            afr[4 + j] = (short)f2bf(h1[j]);
        }
        #pragma unroll
        for (int j = 0; j < 8; ++j) {                // W tiny, L1-hot
            int k = kb + quad * 8 + j;
            b0[j] = (short)f2bf(W[k * UDIM + col]);
            b1[j] = (short)f2bf(W[k * UDIM + 16 + col]);
            b2[j] = (short)f2bf(W[k * UDIM + 32 + col]);
            b3[j] = (short)f2bf(W[k * UDIM + 48 + col]);
        }
        acc0 = __builtin_amdgcn_mfma_f32_16x16x32_bf16(afr, b0, acc0, 0, 0, 0);
        acc1 = __builtin_amdgcn_mfma_f32_16x16x32_bf16(afr, b1, acc1, 0, 0, 0);
        acc2 = __builtin_amdgcn_mfma_f32_16x16x32_bf16(afr, b2, acc2, 0, 0, 0);
        acc3 = __builtin_amdgcn_mfma_f32_16x16x32_bf16(afr, b3, acc3, 0, 0, 0);
    }
    #pragma unroll
    for (int r = 0; r < 4; ++r) {   // C/D: col(u)=lane&15 (+16/group), row=quad*4+r
        Xl[wave][quad * 4 + r][col]      = acc0[r];
        Xl[wave][quad * 4 + r][16 + col] = acc1[r];
        Xl[wave][quad * 4 + r][32 + col] = acc2[r];
        Xl[wave][quad * 4 + r][48 + col] = acc3[r];
    }
    __syncthreads();

    const int b = i0 >> 12, n0 = i0 & (NTOK - 1);
    float ps = 0.f, pt = 0.f;
    #pragma unroll
    for (int ui = 0; ui < 16; ++ui) {
        int u = quad * 16 + ui;
        float x = Xl[wave][col][u];
        ps = fmaf(x, a1[u], ps);
        pt = fmaf(x, a2[u], pt);
    }
    ps += __shfl_xor(ps, 16, 64); ps += __shfl_xor(ps, 32, 64);
    pt += __shfl_xor(pt, 16, 64); pt += __shfl_xor(pt, 32, 64);
    const float LOG2E = 1.44269504f;
    if (quad == 0) s_out[i0 + col] = ps * LOG2E;   // exp2 domain
    if (quad == 1) t_out[i0 + col] = pt * LOG2E;

    #pragma unroll
    for (int ui = 0; ui < 16; ++ui) {
        int u = quad * 16 + ui;
        XT[(size_t)(b * UDIM + u) * NTOK + n0 + col] = f2bf(Xl[wave][col][u]);
    }
}

// ---------------- kernel 2: fused mask+softmax+PV, zero-LDS -----------------
// grid 512 = 8 batches x 64 row-tiles-of-64 (b = bx&7), 4 waves/block.
// Each wave: 16 rows x FULL K (128 steps of 32). No cross-wave reduction.
__global__ __launch_bounds__(256) void attn_kernel(
    const float* __restrict__ A,            // f32 [B, N, N] -- 512 MB stream
    const unsigned short* __restrict__ XT,  // bf16 [B, 64, N] (L2-hot)
    const float* __restrict__ s_in,         // log2e-scaled
    const float* __restrict__ t_in,         // log2e-scaled
    float* __restrict__ out)                // f32 [B, N, 64]
{
    const int tid  = threadIdx.x;
    const int wave = tid >> 6, lane = tid & 63;
    const int bx   = blockIdx.x;
    const int b    = bx & 7;
    const int i0   = (bx >> 3) * 64 + wave * 16;   // this wave's 16 rows
    const int col  = lane & 15, quad = lane >> 4;

    const float s_m = s_in[b * NTOK + i0 + col];   // A-frag row m = lane&15

    const float* aptr = A + ((size_t)(b * NTOK + i0 + col)) * NTOK + quad * 8;
    const float* tptr = t_in + b * NTOK + quad * 8;
    const unsigned short* xb  = XT + (size_t)b * UDIM * NTOK + quad * 8;
    const unsigned short* xp0 = xb + (size_t)(col)      * NTOK;
    const unsigned short* xp1 = xb + (size_t)(16 + col) * NTOK;
    const unsigned short* xp2 = xb + (size_t)(32 + col) * NTOK;
    const unsigned short* xp3 = xb + (size_t)(48 + col) * NTOK;

    f32x4 acc0 = {0,0,0,0}, acc1 = {0,0,0,0}, acc2 = {0,0,0,0}, acc3 = {0,0,0,0};
    float den = 0.f;

    // 1-step register prefetch on the HBM-critical A stream
    f32x4 pa0 = *(const f32x4*)aptr;
    f32x4 pa1 = *(const f32x4*)(aptr + 4);

    #pragma unroll 4
    for (int step = 0; step < 128; ++step) {
        f32x4 am0 = pa0, am1 = pa1;
        if (step < 127) {
            aptr += 32;
            pa0 = *(const f32x4*)aptr;             // in flight across this
            pa1 = *(const f32x4*)(aptr + 4);       // step's VALU+MFMA work
        }
        f32x4 t0  = *(const f32x4*)tptr;           // k = quad*8 + 0..3 (L2-hot)
        f32x4 t1  = *(const f32x4*)(tptr + 4);
        short8 bf0 = *(const short8*)xp0;          // B-frags (L2-hot)
        short8 bf1 = *(const short8*)xp1;
        short8 bf2 = *(const short8*)xp2;
        short8 bf3 = *(const short8*)xp3;

        unsigned uw[8];
        #pragma unroll
        for (int j = 0; j < 4; ++j) {
            float l0 = s_m + t0[j], l1 = s_m + t1[j];
            float e0 = fmaxf(l0, 0.2f * l0);       // lrelu commutes with log2e>0
            float e1 = fmaxf(l1, 0.2f * l1);
            float w0 = __builtin_amdgcn_exp2f(e0) * am0[j];  // masked -> exact 0
            float w1 = __builtin_amdgcn_exp2f(e1) * am1[j];
            den += w0 + w1;
            uw[j]     = __float_as_uint(w0) + 0x8000u;  // round-half-up bf16
            uw[4 + j] = __float_as_uint(w1) + 0x8000u;
        }
        PackU p;   // hi16 pairs: afr[k]=w(k), k=quad*8+j
        p.u[0] = __builtin_amdgcn_perm(uw[1], uw[0], 0x07060302u);
        p.u[1] = __builtin_amdgcn_perm(uw[3], uw[2], 0x07060302u);
        p.u[2] = __builtin_amdgcn_perm(uw[5], uw[4], 0x07060302u);
        p.u[3] = __builtin_amdgcn_perm(uw[7], uw[6], 0x07060302u);

        acc0 = __builtin_amdgcn_mfma_f32_16x16x32_bf16(p.s, bf0, acc0, 0, 0, 0);
        acc1 = __builtin_amdgcn_mfma_f32_16x16x32_bf16(p.s, bf1, acc1, 0, 0, 0);
        acc2 = __builtin_amdgcn_mfma_f32_16x16x32_bf16(p.s, bf2, acc2, 0, 0, 0);
        acc3 = __builtin_amdgcn_mfma_f32_16x16x32_bf16(p.s, bf3, acc3, 0, 0, 0);

        tptr += 32; xp0 += 32; xp1 += 32; xp2 += 32; xp3 += 32;
    }

    // full row denominators: lane (quad,col) -> sum over all 4 quads for row col
    den += __shfl_xor(den, 16, 64);
    den += __shfl_xor(den, 32, 64);

    // epilogue from registers: acc row = quad*4+r, cols u = col + {0,16,32,48}
    #pragma unroll
    for (int r = 0; r < 4; ++r) {
        float dd = __shfl(den, quad * 4 + r, 64);  // den of row quad*4+r
        float inv = 1.0f / dd;
        size_t o = (size_t)(b * NTOK + i0 + quad * 4 + r) * UDIM;
        __builtin_nontemporal_store(fmaxf(acc0[r] * inv, 0.f), &out[o + col]);
        __builtin_nontemporal_store(fmaxf(acc1[r] * inv, 0.f), &out[o + 16 + col]);
        __builtin_nontemporal_store(fmaxf(acc2[r] * inv, 0.f), &out[o + 32 + col]);
        __builtin_nontemporal_store(fmaxf(acc3[r] * inv, 0.f), &out[o + 48 + col]);
    }
}

extern "C" void kernel_launch(void* const* d_in, const int* in_sizes, int n_in,
                              void* d_out, int out_size, void* d_ws, size_t ws_size,
                              hipStream_t stream) {
    const float* H  = (const float*)d_in[0];
    const float* A  = (const float*)d_in[1];
    const float* W  = (const float*)d_in[2];
    const float* a1 = (const float*)d_in[3];
    const float* a2 = (const float*)d_in[4];
    float* out = (float*)d_out;

    char* ws = (char*)d_ws;
    unsigned short* XT = (unsigned short*)ws;                               // 4 MB bf16
    float* s = (float*)(ws + (size_t)BATCH * UDIM * NTOK * 2);              // 128 KB
    float* t = (float*)(ws + (size_t)BATCH * UDIM * NTOK * 2 + (size_t)BATCH * NTOK * 4);

    prep_kernel<<<512, 256, 0, stream>>>(H, W, a1, a2, XT, s, t);
    attn_kernel<<<512, 256, 0, stream>>>(A, XT, s, t, out);
}